// Round 6
// baseline (310.352 us; speedup 1.0000x reference)
//
#include <hip/hip_runtime.h>
#include <cmath>

// GPTNeoXRoutedMLP: N=2048 tokens, H=1024, F=4096, E=8, topk=2.
// R6: weights converted f32->bf16 by pure STREAMING cvt (no transpose) into
// natural [k][col] layout; GEMM B-operand staged via global_load_lds with a
// per-lane source gather into a subtiled LDS layout and consumed through
// hardware-transpose ds_read_b64_tr_b16. A-path = R3-verified (gload_lds +
// XOR swizzle). k-map of B constructed to equal A's (k = kk*32+lg*8+j).

#define H_DIM 1024
#define F_DIM 4096
#define E_NUM 8
#define N_TOK 2048
#define BK 64
#define MAX_SLOTS 5120
#define MAX_MT (MAX_SLOTS / 128)   // 40 row tiles
#define G1_GRID (MAX_MT * 32)      // 1280
#define G2_GRID (MAX_MT * 16)      // 640
#define CVT_BLKS 16384             // 33.55M elems / 2048 per block

typedef short s16x4 __attribute__((ext_vector_type(4)));
typedef short s16x8 __attribute__((ext_vector_type(8)));
typedef float f32x4 __attribute__((ext_vector_type(4)));
typedef __attribute__((address_space(3))) const unsigned short* lds_us;

__device__ __forceinline__ unsigned short f2bf(float f) {
  unsigned int u = __float_as_uint(f);
  u += 0x7fffu + ((u >> 16) & 1u);   // RNE
  return (unsigned short)(u >> 16);
}

__device__ __forceinline__ void gload_lds16(const void* g, void* l) {
  __builtin_amdgcn_global_load_lds(
      (const __attribute__((address_space(1))) unsigned int*)g,
      (__attribute__((address_space(3))) unsigned int*)l, 16, 0, 0);
}

__device__ __forceinline__ int xcd_swz(int orig, int nwg) {
  const int cpx = nwg >> 3;   // nwg multiple of 8 (1280 / 640)
  return (orig & 7) * cpx + (orig >> 3);
}

__device__ __forceinline__ float fast_gelu(float v) {
  const float w = v * (1.0f + 0.044715f * v * v);
  const float t = __expf(-1.5957691216f * w);
  return v / (1.0f + t);
}

// hardware transpose read: lane l elem j <- lds[base + (l&15) + j*16 + (l>>4)*64]
// with per-lane addr = base + 8*l bytes (each 16-lane group reads its own 128B subtile)
template<int OFS>
__device__ __forceinline__ s16x4 trread(lds_us p) {
  s16x4 r;
  asm volatile("ds_read_b64_tr_b16 %0, %1 offset:%2" : "=v"(r) : "v"(p), "i"(OFS));
  return r;
}

template<int KB>  // gemm1: 4 col-groups -> 4 B-frags
__device__ __forceinline__ void ld_b4(lds_us bp, s16x8 bb[4]) {
  s16x4 p0 = trread<KB + 0>(bp),    q0 = trread<KB + 512>(bp);
  s16x4 p1 = trread<KB + 1024>(bp), q1 = trread<KB + 1536>(bp);
  s16x4 p2 = trread<KB + 2048>(bp), q2 = trread<KB + 2560>(bp);
  s16x4 p3 = trread<KB + 3072>(bp), q3 = trread<KB + 3584>(bp);
  bb[0] = __builtin_shufflevector(p0, q0, 0, 1, 2, 3, 4, 5, 6, 7);
  bb[1] = __builtin_shufflevector(p1, q1, 0, 1, 2, 3, 4, 5, 6, 7);
  bb[2] = __builtin_shufflevector(p2, q2, 0, 1, 2, 3, 4, 5, 6, 7);
  bb[3] = __builtin_shufflevector(p3, q3, 0, 1, 2, 3, 4, 5, 6, 7);
}

template<int KB>  // gemm2: 2 col-groups
__device__ __forceinline__ void ld_b2(lds_us bp, s16x8 bb[2]) {
  s16x4 p0 = trread<KB + 0>(bp),    q0 = trread<KB + 512>(bp);
  s16x4 p1 = trread<KB + 1024>(bp), q1 = trread<KB + 1536>(bp);
  bb[0] = __builtin_shufflevector(p0, q0, 0, 1, 2, 3, 4, 5, 6, 7);
  bb[1] = __builtin_shufflevector(p1, q1, 0, 1, 2, 3, 4, 5, 6, 7);
}

// streaming f32 -> bf16, 2048 elems per block (coalesced both sides)
__device__ __forceinline__ void cvt_blk(const float* __restrict__ in,
                                        unsigned short* __restrict__ out, int blk) {
  const size_t i = ((size_t)blk * 256 + threadIdx.x) * 8;
  f32x4 a = *(const f32x4*)(in + i);
  f32x4 c = *(const f32x4*)(in + i + 4);
  s16x8 u;
#pragma unroll
  for (int j = 0; j < 4; ++j) { u[j] = (short)f2bf(a[j]); u[4 + j] = (short)f2bf(c[j]); }
  *(s16x8*)&out[i] = u;
}

// ---------------- prep: w1 cvt (16384) | x cvt (1024) | router (512) ----------------
__global__ __launch_bounds__(256) void prep_k(
    const float* __restrict__ w1, unsigned short* __restrict__ wbf1,
    const float* __restrict__ x, unsigned short* __restrict__ xb,
    const float* __restrict__ rw, int* __restrict__ meta,
    int* __restrict__ topk_e, float* __restrict__ topk_s) {
  const int b = blockIdx.x;
  const int t = threadIdx.x;
  if (b < CVT_BLKS) { cvt_blk(w1, wbf1, b); return; }
  if (b < CVT_BLKS + 1024) { cvt_blk(x, xb, b - CVT_BLKS); return; }
  // router: one token per wave
  const int n = (b - CVT_BLKS - 1024) * 4 + (t >> 6);
  const int l = t & 63;
  float part[E_NUM];
#pragma unroll
  for (int e = 0; e < E_NUM; ++e) part[e] = 0.f;
  const float* xr = x + (size_t)n * H_DIM;
  for (int h = l; h < H_DIM; h += 64) {
    const float xv = xr[h];
    const float* rwr = rw + h * E_NUM;
#pragma unroll
    for (int e = 0; e < E_NUM; ++e) part[e] += xv * rwr[e];
  }
#pragma unroll
  for (int e = 0; e < E_NUM; ++e) {
#pragma unroll
    for (int off = 32; off > 0; off >>= 1) part[e] += __shfl_down(part[e], off);
  }
  if (l == 0) {
    float v0 = -3.4e38f, v1 = -3.4e38f;
    int i0 = 0, i1 = 0;
#pragma unroll
    for (int e = 0; e < E_NUM; ++e) {
      float v = part[e];
      if (v > v0) { v1 = v0; i1 = i0; v0 = v; i0 = e; }   // strict >: lowest index wins
      else if (v > v1) { v1 = v; i1 = e; }
    }
    const float e1 = expf(v1 - v0);
    const float inv = 1.f / (1.f + e1);
    topk_e[2 * n] = i0; topk_e[2 * n + 1] = i1;
    topk_s[2 * n] = inv; topk_s[2 * n + 1] = e1 * inv;
    atomicAdd(&meta[i0], 1);
    atomicAdd(&meta[i1], 1);
  }
}

// ---------------- Scatter ----------------
__global__ __launch_bounds__(256) void scatter_k(
    int* __restrict__ meta, const int* __restrict__ topk_e,
    const float* __restrict__ topk_s, int* __restrict__ slot_token,
    float* __restrict__ slot_score) {
  __shared__ int soff[9];
  __shared__ int scur[8];
  const int t = threadIdx.x;
  if (t == 0) {
    int acc = 0;
    for (int e = 0; e < E_NUM; ++e) {
      soff[e] = acc;
      meta[8 + e] = acc;
      acc += ((meta[e] + 127) / 128) * 128;
    }
    soff[8] = acc;
    meta[16] = acc;
  }
  if (t < 8) scur[t] = 0;
  __syncthreads();
  for (int a = t; a < N_TOK * 2; a += 256) {
    const int e = topk_e[a];
    const int pos = atomicAdd(&scur[e], 1);
    const int slot = soff[e] + pos;
    slot_token[slot] = a >> 1;
    slot_score[slot] = topk_s[a];
  }
}

// B-staging lane->k map (shared by both GEMMs; equals A's map k = kk*32+lg*8+j):
//  region (kk,cg) holds LDS [h][lg][j][c'] (2*4*4*16=512 elems); one gload inst
//  per region; lane ln covers elems ln*8..+7:
//    h=ln>>5, lg=(ln>>3)&3, j=(ln&7)>>1, c''=(ln&1)*8
//    k = kk*32 + lg*8 + h*4 + j ; col = cg*16 + c'' + [0..8)
#define KLANE(l) (((l) >> 3 & 3) * 8 + ((l) >> 5) * 4 + (((l) & 7) >> 1))

// ============ GEMM1 (+w2 cvt tail): h = gelu(xb[gather] @ w1bf + b1) ============
__global__ __launch_bounds__(256, 2) void gemm1_f(
    const unsigned short* __restrict__ xb, const unsigned short* __restrict__ wbf1,
    const float* __restrict__ b1, const int* __restrict__ meta,
    const int* __restrict__ slot_token, unsigned short* __restrict__ hbuf,
    const float* __restrict__ w2, unsigned short* __restrict__ wbf2) {
  __shared__ __align__(16) unsigned short Al[2 * 8192];  // [2][128 rows][64 k]
  __shared__ __align__(16) unsigned short Bl[2 * 8192];  // [2][16 regions][512]
  if (blockIdx.x >= G1_GRID) { cvt_blk(w2, wbf2, blockIdx.x - G1_GRID); return; }
  const int total = meta[16];
  const int wgid = xcd_swz(blockIdx.x, G1_GRID);
  const int mt = wgid >> 5, nt = wgid & 31;
  const int m0 = mt * 128;
  if (m0 >= total) return;
  int exp = 0;
#pragma unroll
  for (int e = 1; e < E_NUM; ++e) if (m0 >= meta[8 + e]) exp = e;
  const int n0 = nt * 128;
  const int t = threadIdx.x, w = t >> 6, l = t & 63;
  const int wm = w >> 1, wn = w & 1, lr = l & 15, lg = l >> 4;
  const int sr = l >> 3, sc = l & 7;

  const unsigned short* srcA[4];
#pragma unroll
  for (int i = 0; i < 4; ++i) {
    const int r = (w * 4 + i) * 8 + sr;
    int tk = slot_token[m0 + r]; if (tk < 0) tk = 0;
    srcA[i] = xb + (size_t)tk * H_DIM + (sc ^ sr) * 8;
  }
  const unsigned short* wbe = wbf1 + (size_t)exp * H_DIM * F_DIM;
  const unsigned short* srcB[4];
#pragma unroll
  for (int i = 0; i < 4; ++i) {
    const int ri = w * 4 + i;                       // region: kk=ri>>3, cg=ri&7
    const int kl = (ri >> 3) * 32 + KLANE(l);
    srcB[i] = wbe + (size_t)kl * F_DIM + n0 + (ri & 7) * 16 + (l & 1) * 8;
  }

  const f32x4 fzero = {0.f, 0.f, 0.f, 0.f};
  f32x4 acc[4][4];
#pragma unroll
  for (int a = 0; a < 4; ++a)
#pragma unroll
    for (int b = 0; b < 4; ++b) acc[a][b] = fzero;

#define GLA1(kt, Ad)                                                        \
  _Pragma("unroll") for (int i = 0; i < 4; ++i)                             \
      gload_lds16(srcA[i] + (kt) * BK, (Ad) + (w * 4 + i) * 512);
#define GLB1(kt, Bd)                                                        \
  _Pragma("unroll") for (int i = 0; i < 4; ++i)                             \
      gload_lds16(srcB[i] + (size_t)(kt) * (BK * F_DIM), (Bd) + (w * 4 + i) * 512);
#define MFMA1(Ac, Bc)                                                       \
  {                                                                         \
    lds_us bp = (lds_us)(Bc) + wn * 2048 + l * 4;                           \
    _Pragma("unroll") for (int kk = 0; kk < 2; ++kk) {                      \
      s16x8 af[4], bb[4];                                                   \
      _Pragma("unroll") for (int fm = 0; fm < 4; ++fm) {                    \
        const int row = wm * 64 + fm * 16 + lr;                             \
        af[fm] = *(const s16x8*)&(Ac)[row * 64 + (((kk * 4 + lg) ^ (lr & 7)) * 8)]; \
      }                                                                     \
      if (kk == 0) ld_b4<0>(bp, bb); else ld_b4<8192>(bp, bb);              \
      asm volatile("s_waitcnt lgkmcnt(0)" ::: "memory");                    \
      __builtin_amdgcn_sched_barrier(0);                                    \
      _Pragma("unroll") for (int fm = 0; fm < 4; ++fm)                      \
        _Pragma("unroll") for (int fn = 0; fn < 4; ++fn)                    \
          acc[fm][fn] = __builtin_amdgcn_mfma_f32_16x16x32_bf16(af[fm], bb[fn], acc[fm][fn], 0, 0, 0); \
    }                                                                       \
  }

  const int NT = H_DIM / BK;  // 16
  GLA1(0, Al) GLB1(0, Bl)
  __syncthreads();
  int cur = 0;
  for (int kt = 0; kt < NT; ++kt) {
    const int nxt = cur ^ 1;
    if (kt + 1 < NT) { GLA1(kt + 1, Al + nxt * 8192) GLB1(kt + 1, Bl + nxt * 8192) }
    MFMA1(Al + cur * 8192, Bl + cur * 8192)
    __syncthreads();
    cur = nxt;
  }
#pragma unroll
  for (int fn = 0; fn < 4; ++fn) {
    const int col = n0 + wn * 64 + fn * 16 + lr;
    const float bias = b1[exp * F_DIM + col];
#pragma unroll
    for (int fm = 0; fm < 4; ++fm) {
      const int rbase = m0 + wm * 64 + fm * 16 + lg * 4;
#pragma unroll
      for (int i = 0; i < 4; ++i) {
        hbuf[(size_t)(rbase + i) * F_DIM + col] = f2bf(fast_gelu(acc[fm][fn][i] + bias));
      }
    }
  }
}

// ============ GEMM2: out[token] += s*(hbuf @ w2bf + b2), BN=64 ============
__global__ __launch_bounds__(256, 3) void gemm2_f(
    const unsigned short* __restrict__ hbuf, const unsigned short* __restrict__ wbf2,
    const float* __restrict__ b2, const int* __restrict__ meta,
    const int* __restrict__ slot_token, const float* __restrict__ slot_score,
    float* __restrict__ out) {
  __shared__ __align__(16) unsigned short Al[2 * 8192];  // [2][128 rows][64 k]
  __shared__ __align__(16) unsigned short Bl[2 * 4096];  // [2][8 regions][512]
  const int total = meta[16];
  const int wgid = xcd_swz(blockIdx.x, G2_GRID);
  const int mt = wgid >> 4, nt = wgid & 15;
  const int m0 = mt * 128;
  if (m0 >= total) return;
  int exp = 0;
#pragma unroll
  for (int e = 1; e < E_NUM; ++e) if (m0 >= meta[8 + e]) exp = e;
  const int n0 = nt * 64;
  const int t = threadIdx.x, w = t >> 6, l = t & 63;
  const int wm = w >> 1, wn = w & 1, lr = l & 15, lg = l >> 4;
  const int sr = l >> 3, sc = l & 7;

  const unsigned short* srcA[4];
#pragma unroll
  for (int i = 0; i < 4; ++i) {
    const int r = (w * 4 + i) * 8 + sr;
    srcA[i] = hbuf + (size_t)(m0 + r) * F_DIM + (sc ^ sr) * 8;
  }
  const unsigned short* wbe = wbf2 + (size_t)exp * F_DIM * H_DIM;
  const unsigned short* srcB[2];
#pragma unroll
  for (int i = 0; i < 2; ++i) {
    const int ri = w * 2 + i;                       // region: kk=ri>>2, cg=ri&3
    const int kl = (ri >> 2) * 32 + KLANE(l);
    srcB[i] = wbe + (size_t)kl * H_DIM + n0 + (ri & 3) * 16 + (l & 1) * 8;
  }

  const f32x4 fzero = {0.f, 0.f, 0.f, 0.f};
  f32x4 acc[4][2];
#pragma unroll
  for (int a = 0; a < 4; ++a)
#pragma unroll
    for (int b = 0; b < 2; ++b) acc[a][b] = fzero;

#define GLA2(kt, Ad)                                                        \
  _Pragma("unroll") for (int i = 0; i < 4; ++i)                             \
      gload_lds16(srcA[i] + (kt) * BK, (Ad) + (w * 4 + i) * 512);
#define GLB2(kt, Bd)                                                        \
  _Pragma("unroll") for (int i = 0; i < 2; ++i)                             \
      gload_lds16(srcB[i] + (size_t)(kt) * (BK * H_DIM), (Bd) + (w * 2 + i) * 512);
#define MFMA2(Ac, Bc)                                                       \
  {                                                                         \
    lds_us bp = (lds_us)(Bc) + wn * 1024 + l * 4;                           \
    _Pragma("unroll") for (int kk = 0; kk < 2; ++kk) {                      \
      s16x8 af[4], bb[2];                                                   \
      _Pragma("unroll") for (int fm = 0; fm < 4; ++fm) {                    \
        const int row = wm * 64 + fm * 16 + lr;                             \
        af[fm] = *(const s16x8*)&(Ac)[row * 64 + (((kk * 4 + lg) ^ (lr & 7)) * 8)]; \
      }                                                                     \
      if (kk == 0) ld_b2<0>(bp, bb); else ld_b2<4096>(bp, bb);              \
      asm volatile("s_waitcnt lgkmcnt(0)" ::: "memory");                    \
      __builtin_amdgcn_sched_barrier(0);                                    \
      _Pragma("unroll") for (int fm = 0; fm < 4; ++fm)                      \
        _Pragma("unroll") for (int fn = 0; fn < 2; ++fn)                    \
          acc[fm][fn] = __builtin_amdgcn_mfma_f32_16x16x32_bf16(af[fm], bb[fn], acc[fm][fn], 0, 0, 0); \
    }                                                                       \
  }

  const int NT = F_DIM / BK;  // 64
  GLA2(0, Al) GLB2(0, Bl)
  __syncthreads();
  int cur = 0;
  for (int kt = 0; kt < NT; ++kt) {
    const int nxt = cur ^ 1;
    if (kt + 1 < NT) { GLA2(kt + 1, Al + nxt * 8192) GLB2(kt + 1, Bl + nxt * 4096) }
    MFMA2(Al + cur * 8192, Bl + cur * 4096)
    __syncthreads();
    cur = nxt;
  }
#pragma unroll
  for (int fm = 0; fm < 4; ++fm) {
    const int rbase = m0 + wm * 64 + fm * 16 + lg * 4;
    int toks[4]; float ss[4];
#pragma unroll
    for (int i = 0; i < 4; ++i) {
      toks[i] = slot_token[rbase + i];
      ss[i] = slot_score[rbase + i];
    }
#pragma unroll
    for (int fn = 0; fn < 2; ++fn) {
      const int col = n0 + wn * 32 + fn * 16 + lr;
      const float b2v = b2[exp * H_DIM + col];
#pragma unroll
      for (int i = 0; i < 4; ++i) {
        if (toks[i] >= 0)
          atomicAdd(out + (size_t)toks[i] * H_DIM + col, ss[i] * (acc[fm][fn][i] + b2v));
      }
    }
  }
}

// standalone w2 cvt for the low-ws sequential path
__global__ __launch_bounds__(256) void cvt2_k(const float* __restrict__ in,
                                              unsigned short* __restrict__ out) {
  cvt_blk(in, out, blockIdx.x);
}

extern "C" void kernel_launch(void* const* d_in, const int* in_sizes, int n_in,
                              void* d_out, int out_size, void* d_ws, size_t ws_size,
                              hipStream_t stream) {
  const float* x  = (const float*)d_in[0];
  const float* rw = (const float*)d_in[1];
  const float* w1 = (const float*)d_in[2];
  const float* b1 = (const float*)d_in[3];
  const float* w2 = (const float*)d_in[4];
  const float* b2 = (const float*)d_in[5];
  float* out = (float*)d_out;
  char* ws = (char*)d_ws;

  int*   meta       = (int*)ws;
  int*   topk_e     = (int*)(ws + 4096);
  float* topk_s     = (float*)(ws + 20480);
  int*   slot_token = (int*)(ws + 36864);
  float* slot_score = (float*)(ws + 57344);
  unsigned short* xb   = (unsigned short*)(ws + (1ull << 20));
  unsigned short* hbuf = (unsigned short*)(ws + (8ull << 20));
  unsigned short* wbf1 = (unsigned short*)(ws + (48ull << 20));
  const size_t W = (size_t)E_NUM * H_DIM * F_DIM * 2;     // 64 MiB
  unsigned short* wbf2 = (unsigned short*)(ws + (48ull << 20) + W);
  const bool full = ws_size >= (48ull << 20) + 2 * W;     // 176 MiB
  if (!full) wbf2 = wbf1;   // sequential reuse

  hipMemsetAsync(meta, 0, 256, stream);
  hipMemsetAsync(slot_token, 0xFF, MAX_SLOTS * sizeof(int), stream);
  hipMemsetAsync(out, 0, (size_t)N_TOK * H_DIM * sizeof(float), stream);

  prep_k<<<CVT_BLKS + 1024 + 512, 256, 0, stream>>>(w1, wbf1, x, xb, rw, meta, topk_e, topk_s);
  scatter_k<<<1, 256, 0, stream>>>(meta, topk_e, topk_s, slot_token, slot_score);

  if (full) {
    gemm1_f<<<G1_GRID + CVT_BLKS, 256, 0, stream>>>(xb, wbf1, b1, meta, slot_token, hbuf, w2, wbf2);
  } else {
    gemm1_f<<<G1_GRID, 256, 0, stream>>>(xb, wbf1, b1, meta, slot_token, hbuf, w2, wbf2);
    cvt2_k<<<CVT_BLKS, 256, 0, stream>>>(w2, wbf2);
  }
  gemm2_f<<<G2_GRID, 256, 0, stream>>>(hbuf, wbf2, b2, meta, slot_token, slot_score, out);
}

// Round 7
// 274.451 us; speedup vs baseline: 1.1308x; 1.1308x over previous
//
#include <hip/hip_runtime.h>
#include <cmath>

// GPTNeoXRoutedMLP: N=2048 tokens, H=1024, F=4096, E=8, topk=2.
// R7: remove router's same-line device atomics (the ~110us serialization floor);
// scatter builds the histogram in-block. Grid-stride fat streaming cvt blocks.
// GEMMs = R6 (gload_lds A + XOR swizzle; B via subtiled LDS + ds_read_b64_tr_b16).

#define H_DIM 1024
#define F_DIM 4096
#define E_NUM 8
#define N_TOK 2048
#define BK 64
#define MAX_SLOTS 5120
#define MAX_MT (MAX_SLOTS / 128)   // 40 row tiles
#define G1_GRID (MAX_MT * 32)      // 1280
#define G2_GRID (MAX_MT * 16)      // 640
#define CVT_BLKS 2048              // grid-stride blocks per weight tensor
#define WCHUNKS (E_NUM * H_DIM * F_DIM / 8)   // 4194304
#define XCHUNKS (N_TOK * H_DIM / 8)           // 262144

typedef short s16x4 __attribute__((ext_vector_type(4)));
typedef short s16x8 __attribute__((ext_vector_type(8)));
typedef float f32x4 __attribute__((ext_vector_type(4)));
typedef __attribute__((address_space(3))) const unsigned short* lds_us;

__device__ __forceinline__ unsigned short f2bf(float f) {
  unsigned int u = __float_as_uint(f);
  u += 0x7fffu + ((u >> 16) & 1u);   // RNE
  return (unsigned short)(u >> 16);
}

__device__ __forceinline__ void gload_lds16(const void* g, void* l) {
  __builtin_amdgcn_global_load_lds(
      (const __attribute__((address_space(1))) unsigned int*)g,
      (__attribute__((address_space(3))) unsigned int*)l, 16, 0, 0);
}

__device__ __forceinline__ int xcd_swz(int orig, int nwg) {
  const int cpx = nwg >> 3;   // nwg multiple of 8 (1280 / 640)
  return (orig & 7) * cpx + (orig >> 3);
}

__device__ __forceinline__ float fast_gelu(float v) {
  const float w = v * (1.0f + 0.044715f * v * v);
  const float t = __expf(-1.5957691216f * w);
  return v / (1.0f + t);
}

// hardware transpose read: lane l elem j <- lds[base + (l&15) + j*16 + (l>>4)*64]
template<int OFS>
__device__ __forceinline__ s16x4 trread(lds_us p) {
  s16x4 r;
  asm volatile("ds_read_b64_tr_b16 %0, %1 offset:%2" : "=v"(r) : "v"(p), "i"(OFS));
  return r;
}

template<int KB>  // gemm1: 4 col-groups -> 4 B-frags
__device__ __forceinline__ void ld_b4(lds_us bp, s16x8 bb[4]) {
  s16x4 p0 = trread<KB + 0>(bp),    q0 = trread<KB + 512>(bp);
  s16x4 p1 = trread<KB + 1024>(bp), q1 = trread<KB + 1536>(bp);
  s16x4 p2 = trread<KB + 2048>(bp), q2 = trread<KB + 2560>(bp);
  s16x4 p3 = trread<KB + 3072>(bp), q3 = trread<KB + 3584>(bp);
  bb[0] = __builtin_shufflevector(p0, q0, 0, 1, 2, 3, 4, 5, 6, 7);
  bb[1] = __builtin_shufflevector(p1, q1, 0, 1, 2, 3, 4, 5, 6, 7);
  bb[2] = __builtin_shufflevector(p2, q2, 0, 1, 2, 3, 4, 5, 6, 7);
  bb[3] = __builtin_shufflevector(p3, q3, 0, 1, 2, 3, 4, 5, 6, 7);
}

template<int KB>  // gemm2: 2 col-groups
__device__ __forceinline__ void ld_b2(lds_us bp, s16x8 bb[2]) {
  s16x4 p0 = trread<KB + 0>(bp),    q0 = trread<KB + 512>(bp);
  s16x4 p1 = trread<KB + 1024>(bp), q1 = trread<KB + 1536>(bp);
  bb[0] = __builtin_shufflevector(p0, q0, 0, 1, 2, 3, 4, 5, 6, 7);
  bb[1] = __builtin_shufflevector(p1, q1, 0, 1, 2, 3, 4, 5, 6, 7);
}

// grid-stride streaming f32 -> bf16 (coalesced both sides, stable waves)
__device__ __forceinline__ void cvt_stream(const float* __restrict__ in,
                                           unsigned short* __restrict__ out,
                                           int blk, int nblk, int nchunks) {
  const int step = nblk * 256;
#pragma unroll 2
  for (int c = blk * 256 + threadIdx.x; c < nchunks; c += step) {
    const size_t i = (size_t)c * 8;
    f32x4 a = *(const f32x4*)(in + i);
    f32x4 b = *(const f32x4*)(in + i + 4);
    s16x8 u;
#pragma unroll
    for (int j = 0; j < 4; ++j) { u[j] = (short)f2bf(a[j]); u[4 + j] = (short)f2bf(b[j]); }
    *(s16x8*)&out[i] = u;
  }
}

// ---------------- prep: w1 cvt (2048) | x cvt (128) | router (512, NO atomics) ----------------
__global__ __launch_bounds__(256) void prep_k(
    const float* __restrict__ w1, unsigned short* __restrict__ wbf1,
    const float* __restrict__ x, unsigned short* __restrict__ xb,
    const float* __restrict__ rw, int* __restrict__ topk_e, float* __restrict__ topk_s) {
  const int b = blockIdx.x;
  const int t = threadIdx.x;
  if (b < CVT_BLKS) { cvt_stream(w1, wbf1, b, CVT_BLKS, WCHUNKS); return; }
  if (b < CVT_BLKS + 128) { cvt_stream(x, xb, b - CVT_BLKS, 128, XCHUNKS); return; }
  // router: one token per wave, results written, counts done later in scatter_k
  const int n = (b - CVT_BLKS - 128) * 4 + (t >> 6);
  const int l = t & 63;
  float part[E_NUM];
#pragma unroll
  for (int e = 0; e < E_NUM; ++e) part[e] = 0.f;
  const float* xr = x + (size_t)n * H_DIM;
  for (int h = l; h < H_DIM; h += 64) {
    const float xv = xr[h];
    const float* rwr = rw + h * E_NUM;
#pragma unroll
    for (int e = 0; e < E_NUM; ++e) part[e] += xv * rwr[e];
  }
#pragma unroll
  for (int e = 0; e < E_NUM; ++e) {
#pragma unroll
    for (int off = 32; off > 0; off >>= 1) part[e] += __shfl_down(part[e], off);
  }
  if (l == 0) {
    float v0 = -3.4e38f, v1 = -3.4e38f;
    int i0 = 0, i1 = 0;
#pragma unroll
    for (int e = 0; e < E_NUM; ++e) {
      float v = part[e];
      if (v > v0) { v1 = v0; i1 = i0; v0 = v; i0 = e; }   // strict >: lowest index wins
      else if (v > v1) { v1 = v; i1 = e; }
    }
    const float e1 = expf(v1 - v0);
    const float inv = 1.f / (1.f + e1);
    topk_e[2 * n] = i0; topk_e[2 * n + 1] = i1;
    topk_s[2 * n] = inv; topk_s[2 * n + 1] = e1 * inv;
  }
}

// ------- Scatter: in-block histogram (wave-sharded LDS), padded offsets, slots -------
__global__ __launch_bounds__(256) void scatter_k(
    int* __restrict__ meta, const int* __restrict__ topk_e,
    const float* __restrict__ topk_s, int* __restrict__ slot_token,
    float* __restrict__ slot_score) {
  __shared__ int cnt[4][8];   // per-wave shards
  __shared__ int soff[9];
  __shared__ int scur[8];
  const int t = threadIdx.x;
  const int wv = t >> 6;
  if (t < 32) cnt[t >> 3][t & 7] = 0;
  if (t < 8) scur[t] = 0;
  __syncthreads();
  for (int a = t; a < N_TOK * 2; a += 256)
    atomicAdd(&cnt[wv][topk_e[a]], 1);
  __syncthreads();
  if (t == 0) {
    int acc = 0;
    for (int e = 0; e < E_NUM; ++e) {
      const int c = cnt[0][e] + cnt[1][e] + cnt[2][e] + cnt[3][e];
      soff[e] = acc;
      meta[8 + e] = acc;
      acc += ((c + 127) / 128) * 128;
    }
    soff[8] = acc;
    meta[16] = acc;
  }
  __syncthreads();
  for (int a = t; a < N_TOK * 2; a += 256) {
    const int e = topk_e[a];
    const int pos = atomicAdd(&scur[e], 1);
    const int slot = soff[e] + pos;
    slot_token[slot] = a >> 1;
    slot_score[slot] = topk_s[a];
  }
}

// B-staging lane->k map (shared by both GEMMs; equals A's map k = kk*32+lg*8+j)
#define KLANE(l) (((l) >> 3 & 3) * 8 + ((l) >> 5) * 4 + (((l) & 7) >> 1))

// ============ GEMM1 (+w2 cvt tail): h = gelu(xb[gather] @ w1bf + b1) ============
__global__ __launch_bounds__(256, 2) void gemm1_f(
    const unsigned short* __restrict__ xb, const unsigned short* __restrict__ wbf1,
    const float* __restrict__ b1, const int* __restrict__ meta,
    const int* __restrict__ slot_token, unsigned short* __restrict__ hbuf,
    const float* __restrict__ w2, unsigned short* __restrict__ wbf2) {
  __shared__ __align__(16) unsigned short Al[2 * 8192];  // [2][128 rows][64 k]
  __shared__ __align__(16) unsigned short Bl[2 * 8192];  // [2][16 regions][512]
  if (blockIdx.x >= G1_GRID) {   // fused tail: w2 f32 -> bf16 streaming
    cvt_stream(w2, wbf2, blockIdx.x - G1_GRID, CVT_BLKS, WCHUNKS);
    return;
  }
  const int total = meta[16];
  const int wgid = xcd_swz(blockIdx.x, G1_GRID);
  const int mt = wgid >> 5, nt = wgid & 31;
  const int m0 = mt * 128;
  if (m0 >= total) return;
  int exp = 0;
#pragma unroll
  for (int e = 1; e < E_NUM; ++e) if (m0 >= meta[8 + e]) exp = e;
  const int n0 = nt * 128;
  const int t = threadIdx.x, w = t >> 6, l = t & 63;
  const int wm = w >> 1, wn = w & 1, lr = l & 15, lg = l >> 4;
  const int sr = l >> 3, sc = l & 7;

  const unsigned short* srcA[4];
#pragma unroll
  for (int i = 0; i < 4; ++i) {
    const int r = (w * 4 + i) * 8 + sr;
    int tk = slot_token[m0 + r]; if (tk < 0) tk = 0;
    srcA[i] = xb + (size_t)tk * H_DIM + (sc ^ sr) * 8;
  }
  const unsigned short* wbe = wbf1 + (size_t)exp * H_DIM * F_DIM;
  const unsigned short* srcB[4];
#pragma unroll
  for (int i = 0; i < 4; ++i) {
    const int ri = w * 4 + i;                       // region: kk=ri>>3, cg=ri&7
    const int kl = (ri >> 3) * 32 + KLANE(l);
    srcB[i] = wbe + (size_t)kl * F_DIM + n0 + (ri & 7) * 16 + (l & 1) * 8;
  }

  const f32x4 fzero = {0.f, 0.f, 0.f, 0.f};
  f32x4 acc[4][4];
#pragma unroll
  for (int a = 0; a < 4; ++a)
#pragma unroll
    for (int b = 0; b < 4; ++b) acc[a][b] = fzero;

#define GLA1(kt, Ad)                                                        \
  _Pragma("unroll") for (int i = 0; i < 4; ++i)                             \
      gload_lds16(srcA[i] + (kt) * BK, (Ad) + (w * 4 + i) * 512);
#define GLB1(kt, Bd)                                                        \
  _Pragma("unroll") for (int i = 0; i < 4; ++i)                             \
      gload_lds16(srcB[i] + (size_t)(kt) * (BK * F_DIM), (Bd) + (w * 4 + i) * 512);
#define MFMA1(Ac, Bc)                                                       \
  {                                                                         \
    lds_us bp = (lds_us)(Bc) + wn * 2048 + l * 4;                           \
    _Pragma("unroll") for (int kk = 0; kk < 2; ++kk) {                      \
      s16x8 af[4], bb[4];                                                   \
      _Pragma("unroll") for (int fm = 0; fm < 4; ++fm) {                    \
        const int row = wm * 64 + fm * 16 + lr;                             \
        af[fm] = *(const s16x8*)&(Ac)[row * 64 + (((kk * 4 + lg) ^ (lr & 7)) * 8)]; \
      }                                                                     \
      if (kk == 0) ld_b4<0>(bp, bb); else ld_b4<8192>(bp, bb);              \
      asm volatile("s_waitcnt lgkmcnt(0)" ::: "memory");                    \
      __builtin_amdgcn_sched_barrier(0);                                    \
      _Pragma("unroll") for (int fm = 0; fm < 4; ++fm)                      \
        _Pragma("unroll") for (int fn = 0; fn < 4; ++fn)                    \
          acc[fm][fn] = __builtin_amdgcn_mfma_f32_16x16x32_bf16(af[fm], bb[fn], acc[fm][fn], 0, 0, 0); \
    }                                                                       \
  }

  const int NT = H_DIM / BK;  // 16
  GLA1(0, Al) GLB1(0, Bl)
  __syncthreads();
  int cur = 0;
  for (int kt = 0; kt < NT; ++kt) {
    const int nxt = cur ^ 1;
    if (kt + 1 < NT) { GLA1(kt + 1, Al + nxt * 8192) GLB1(kt + 1, Bl + nxt * 8192) }
    MFMA1(Al + cur * 8192, Bl + cur * 8192)
    __syncthreads();
    cur = nxt;
  }
#pragma unroll
  for (int fn = 0; fn < 4; ++fn) {
    const int col = n0 + wn * 64 + fn * 16 + lr;
    const float bias = b1[exp * F_DIM + col];
#pragma unroll
    for (int fm = 0; fm < 4; ++fm) {
      const int rbase = m0 + wm * 64 + fm * 16 + lg * 4;
#pragma unroll
      for (int i = 0; i < 4; ++i) {
        hbuf[(size_t)(rbase + i) * F_DIM + col] = f2bf(fast_gelu(acc[fm][fn][i] + bias));
      }
    }
  }
}

// ============ GEMM2: out[token] += s*(hbuf @ w2bf + b2), BN=64 ============
__global__ __launch_bounds__(256, 3) void gemm2_f(
    const unsigned short* __restrict__ hbuf, const unsigned short* __restrict__ wbf2,
    const float* __restrict__ b2, const int* __restrict__ meta,
    const int* __restrict__ slot_token, const float* __restrict__ slot_score,
    float* __restrict__ out) {
  __shared__ __align__(16) unsigned short Al[2 * 8192];  // [2][128 rows][64 k]
  __shared__ __align__(16) unsigned short Bl[2 * 4096];  // [2][8 regions][512]
  const int total = meta[16];
  const int wgid = xcd_swz(blockIdx.x, G2_GRID);
  const int mt = wgid >> 4, nt = wgid & 15;
  const int m0 = mt * 128;
  if (m0 >= total) return;
  int exp = 0;
#pragma unroll
  for (int e = 1; e < E_NUM; ++e) if (m0 >= meta[8 + e]) exp = e;
  const int n0 = nt * 64;
  const int t = threadIdx.x, w = t >> 6, l = t & 63;
  const int wm = w >> 1, wn = w & 1, lr = l & 15, lg = l >> 4;
  const int sr = l >> 3, sc = l & 7;

  const unsigned short* srcA[4];
#pragma unroll
  for (int i = 0; i < 4; ++i) {
    const int r = (w * 4 + i) * 8 + sr;
    srcA[i] = hbuf + (size_t)(m0 + r) * F_DIM + (sc ^ sr) * 8;
  }
  const unsigned short* wbe = wbf2 + (size_t)exp * F_DIM * H_DIM;
  const unsigned short* srcB[2];
#pragma unroll
  for (int i = 0; i < 2; ++i) {
    const int ri = w * 2 + i;                       // region: kk=ri>>2, cg=ri&3
    const int kl = (ri >> 2) * 32 + KLANE(l);
    srcB[i] = wbe + (size_t)kl * H_DIM + n0 + (ri & 3) * 16 + (l & 1) * 8;
  }

  const f32x4 fzero = {0.f, 0.f, 0.f, 0.f};
  f32x4 acc[4][2];
#pragma unroll
  for (int a = 0; a < 4; ++a)
#pragma unroll
    for (int b = 0; b < 2; ++b) acc[a][b] = fzero;

#define GLA2(kt, Ad)                                                        \
  _Pragma("unroll") for (int i = 0; i < 4; ++i)                             \
      gload_lds16(srcA[i] + (kt) * BK, (Ad) + (w * 4 + i) * 512);
#define GLB2(kt, Bd)                                                        \
  _Pragma("unroll") for (int i = 0; i < 2; ++i)                             \
      gload_lds16(srcB[i] + (size_t)(kt) * (BK * H_DIM), (Bd) + (w * 2 + i) * 512);
#define MFMA2(Ac, Bc)                                                       \
  {                                                                         \
    lds_us bp = (lds_us)(Bc) + wn * 1024 + l * 4;                           \
    _Pragma("unroll") for (int kk = 0; kk < 2; ++kk) {                      \
      s16x8 af[4], bb[2];                                                   \
      _Pragma("unroll") for (int fm = 0; fm < 4; ++fm) {                    \
        const int row = wm * 64 + fm * 16 + lr;                             \
        af[fm] = *(const s16x8*)&(Ac)[row * 64 + (((kk * 4 + lg) ^ (lr & 7)) * 8)]; \
      }                                                                     \
      if (kk == 0) ld_b2<0>(bp, bb); else ld_b2<4096>(bp, bb);              \
      asm volatile("s_waitcnt lgkmcnt(0)" ::: "memory");                    \
      __builtin_amdgcn_sched_barrier(0);                                    \
      _Pragma("unroll") for (int fm = 0; fm < 4; ++fm)                      \
        _Pragma("unroll") for (int fn = 0; fn < 2; ++fn)                    \
          acc[fm][fn] = __builtin_amdgcn_mfma_f32_16x16x32_bf16(af[fm], bb[fn], acc[fm][fn], 0, 0, 0); \
    }                                                                       \
  }

  const int NT = F_DIM / BK;  // 64
  GLA2(0, Al) GLB2(0, Bl)
  __syncthreads();
  int cur = 0;
  for (int kt = 0; kt < NT; ++kt) {
    const int nxt = cur ^ 1;
    if (kt + 1 < NT) { GLA2(kt + 1, Al + nxt * 8192) GLB2(kt + 1, Bl + nxt * 4096) }
    MFMA2(Al + cur * 8192, Bl + cur * 4096)
    __syncthreads();
    cur = nxt;
  }
#pragma unroll
  for (int fm = 0; fm < 4; ++fm) {
    const int rbase = m0 + wm * 64 + fm * 16 + lg * 4;
    int toks[4]; float ss[4];
#pragma unroll
    for (int i = 0; i < 4; ++i) {
      toks[i] = slot_token[rbase + i];
      ss[i] = slot_score[rbase + i];
    }
#pragma unroll
    for (int fn = 0; fn < 2; ++fn) {
      const int col = n0 + wn * 32 + fn * 16 + lr;
      const float b2v = b2[exp * H_DIM + col];
#pragma unroll
      for (int i = 0; i < 4; ++i) {
        if (toks[i] >= 0)
          atomicAdd(out + (size_t)toks[i] * H_DIM + col, ss[i] * (acc[fm][fn][i] + b2v));
      }
    }
  }
}

// standalone w2 cvt for the low-ws sequential path
__global__ __launch_bounds__(256) void cvt2_k(const float* __restrict__ in,
                                              unsigned short* __restrict__ out) {
  cvt_stream(in, out, blockIdx.x, CVT_BLKS, WCHUNKS);
}

extern "C" void kernel_launch(void* const* d_in, const int* in_sizes, int n_in,
                              void* d_out, int out_size, void* d_ws, size_t ws_size,
                              hipStream_t stream) {
  const float* x  = (const float*)d_in[0];
  const float* rw = (const float*)d_in[1];
  const float* w1 = (const float*)d_in[2];
  const float* b1 = (const float*)d_in[3];
  const float* w2 = (const float*)d_in[4];
  const float* b2 = (const float*)d_in[5];
  float* out = (float*)d_out;
  char* ws = (char*)d_ws;

  int*   meta       = (int*)ws;
  int*   topk_e     = (int*)(ws + 4096);
  float* topk_s     = (float*)(ws + 20480);
  int*   slot_token = (int*)(ws + 36864);
  float* slot_score = (float*)(ws + 57344);
  unsigned short* xb   = (unsigned short*)(ws + (1ull << 20));
  unsigned short* hbuf = (unsigned short*)(ws + (8ull << 20));
  unsigned short* wbf1 = (unsigned short*)(ws + (48ull << 20));
  const size_t W = (size_t)E_NUM * H_DIM * F_DIM * 2;     // 64 MiB
  unsigned short* wbf2 = (unsigned short*)(ws + (48ull << 20) + W);
  const bool full = ws_size >= (48ull << 20) + 2 * W;     // 176 MiB
  if (!full) wbf2 = wbf1;   // sequential reuse

  hipMemsetAsync(meta, 0, 256, stream);
  hipMemsetAsync(slot_token, 0xFF, MAX_SLOTS * sizeof(int), stream);
  hipMemsetAsync(out, 0, (size_t)N_TOK * H_DIM * sizeof(float), stream);

  prep_k<<<CVT_BLKS + 128 + 512, 256, 0, stream>>>(w1, wbf1, x, xb, rw, topk_e, topk_s);
  scatter_k<<<1, 256, 0, stream>>>(meta, topk_e, topk_s, slot_token, slot_score);

  if (full) {
    gemm1_f<<<G1_GRID + CVT_BLKS, 256, 0, stream>>>(xb, wbf1, b1, meta, slot_token, hbuf, w2, wbf2);
  } else {
    gemm1_f<<<G1_GRID, 256, 0, stream>>>(xb, wbf1, b1, meta, slot_token, hbuf, w2, wbf2);
    cvt2_k<<<CVT_BLKS, 256, 0, stream>>>(w2, wbf2);
  }
  gemm2_f<<<G2_GRID, 256, 0, stream>>>(hbuf, wbf2, b2, meta, slot_token, slot_score, out);
}